// Round 5
// baseline (289.308 us; speedup 1.0000x reference)
//
#include <hip/hip_runtime.h>
#include <hip/hip_bf16.h>
#include <stdint.h>

// Problem constants
#define NT 4096      // tokens
#define DM 320       // model dim
#define NH 8         // heads
#define DH 40        // head dim
#define DHP 64       // padded head dim for Q/K (K pads zeroed; MFMA K=32 x2)
#define DVP 48       // padded head dim rows for V^T (rows 40..47 garbage, discarded)
#define KS 4         // split-K factor over the key dimension
#define QSCALE 0.22811013f  // (1/sqrt(40)) * log2(e): folded into Q so p = exp2(qk)
#define KSTR 68      // K-tile LDS row stride (ushorts): 34 dwords == 2 mod 32 -> <=2-way
#define PSTR 70      // P-tile LDS row stride (ushorts): 35 dwords, odd -> <=2-way

typedef float f32x4 __attribute__((ext_vector_type(4)));
typedef __bf16 bf16x8 __attribute__((ext_vector_type(8)));

__device__ __forceinline__ unsigned short f2b(float f) {
  unsigned u = __builtin_bit_cast(unsigned, f);
  u += 0x7FFFu + ((u >> 16) & 1u);   // RNE
  return (unsigned short)(u >> 16);
}

__device__ __forceinline__ bf16x8 ld_bf8(const unsigned short* p) {
  uint4 v = *(const uint4*)p;        // 16B load
  return __builtin_bit_cast(bf16x8, v);
}

__device__ __forceinline__ f32x4 mfma16(bf16x8 a, bf16x8 b, f32x4 c) {
  return __builtin_amdgcn_mfma_f32_16x16x32_bf16(a, b, c, 0, 0, 0);
}

__device__ __forceinline__ float fexp2(float x) {
#if __has_builtin(__builtin_amdgcn_exp2f)
  return __builtin_amdgcn_exp2f(x);
#else
  float r; asm("v_exp_f32 %0, %1" : "=v"(r) : "v"(x)); return r;
#endif
}

// ---------------- kernel 1a: phase signatures (packed bytes) ----------------
__global__ __launch_bounds__(256) void sig_kernel(const float* __restrict__ g,
                                                  unsigned char* __restrict__ sigb) {
  int i = blockIdx.x * 256 + threadIdx.x;
  if (i < NT) {
    unsigned s = 0;
    if (g[i] != 0.f)          s |= 1u;
    if (g[NT + i] != 0.f)     s |= 2u;
    if (g[2 * NT + i] != 0.f) s |= 4u;
    sigb[i] = (unsigned char)s;
  }
}

// ---------------- kernel 1b: x -> bf16 ----------------
__global__ __launch_bounds__(256) void cvt_x(const float* __restrict__ x,
                                             unsigned short* __restrict__ xb) {
  int i = (blockIdx.x * 256 + threadIdx.x) * 4;   // < NT*DM
  float4 v = *(const float4*)(x + i);
  ushort4 u;
  u.x = f2b(v.x); u.y = f2b(v.y); u.z = f2b(v.z); u.w = f2b(v.w);
  *(ushort4*)(xb + i) = u;
}

// ---------------- kernel 1c: weights -> bf16, transposed ----------------
// Wt[1280][320]: rows 0..319 Wq^T, 320..639 Wk^T, 640..959 Wv^T, 960..1279 Wo^T.
__global__ __launch_bounds__(256) void cvt_w(
    const float* __restrict__ Wq, const float* __restrict__ Wk,
    const float* __restrict__ Wv, const float* __restrict__ Wo,
    unsigned short* __restrict__ Wt) {
  __shared__ __align__(16) unsigned short lt[64 * 72];
  const int t = threadIdx.x;
  const int kx = blockIdx.x;      // 0..4  (k-tile)
  const int cy = blockIdx.y;      // 0..19 (c-tile across the 4 matrices)
  const int cm = cy % 5;          // c-tile within its matrix
  const float* src;
  int rowbase;
  if (cy < 5)       { src = Wq; rowbase = cm * 64; }
  else if (cy < 10) { src = Wk; rowbase = 320 + cm * 64; }
  else if (cy < 15) { src = Wv; rowbase = 640 + cm * 64; }
  else              { src = Wo; rowbase = 960 + cm * 64; }
  const int c0 = cm * 64;         // column offset within the source matrix (BUGFIX r4)
  const int k0 = kx * 64;
#pragma unroll
  for (int i = 0; i < 4; ++i) {   // read 64k x 64c fp32, transpose into LDS bf16
    int kr = (t >> 4) + i * 16, cc = (t & 15) * 4;
    float4 w4 = *(const float4*)&src[(size_t)(k0 + kr) * DM + c0 + cc];
    lt[(cc + 0) * 72 + kr] = f2b(w4.x);
    lt[(cc + 1) * 72 + kr] = f2b(w4.y);
    lt[(cc + 2) * 72 + kr] = f2b(w4.z);
    lt[(cc + 3) * 72 + kr] = f2b(w4.w);
  }
  __syncthreads();
#pragma unroll
  for (int i = 0; i < 2; ++i) {   // write 64c rows, k-contiguous
    int idx = t + i * 256, cl = idx >> 3, ch = idx & 7;
    *(uint4*)&Wt[(size_t)(rowbase + cl) * DM + k0 + ch * 8] =
        *(const uint4*)&lt[cl * 72 + ch * 8];
  }
}

// ---------------- kernel 2: fused QKV projection (LDS-free, frags from L2) ----------------
// Q stored [h][n][DHP] bf16 PRE-SCALED by QSCALE; K stored [h][n][DHP] (pads zeroed);
// V stored transposed [h][DVP][n] bf16 (rows 40..47 unwritten, discarded later).
__global__ __launch_bounds__(256, 4) void qkv_gemm(
    const unsigned short* __restrict__ xb, const unsigned short* __restrict__ Wt,
    unsigned short* __restrict__ Qb, unsigned short* __restrict__ Kb,
    unsigned short* __restrict__ Vtb) {
  const int t = threadIdx.x;
  const int w = t >> 6, lane = t & 63, quad = lane >> 4, ln = lane & 15;
  const int m0 = blockIdx.x * 64;
  const int cy = blockIdx.y;                  // 0..14
  const int a = cy / 5;                       // 0=Q 1=K 2=V
  const int cc0 = (cy % 5) * 64;
  const unsigned short* Arow = xb + (size_t)(m0 + w * 16 + ln) * DM + quad * 8;
  const unsigned short* Brow = Wt + (size_t)(a * 320 + cc0 + ln) * DM + quad * 8;

  f32x4 acc[4] = {{0,0,0,0},{0,0,0,0},{0,0,0,0},{0,0,0,0}};
  for (int kc = 0; kc < 10; ++kc) {
    bf16x8 af = ld_bf8(Arow + kc * 32);
#pragma unroll
    for (int nt = 0; nt < 4; ++nt) {
      bf16x8 bf = ld_bf8(Brow + (size_t)nt * 16 * DM + kc * 32);
      acc[nt] = mfma16(af, bf, acc[nt]);
    }
  }
#pragma unroll
  for (int nt = 0; nt < 4; ++nt) {
#pragma unroll
    for (int r = 0; r < 4; ++r) {
      int row = m0 + w * 16 + quad * 4 + r;   // D row = quad*4+reg
      int cc = cc0 + nt * 16 + ln;            // D col = lane&15
      int h = cc / DH, d = cc % DH;
      float av = (a == 0) ? acc[nt][r] * QSCALE : acc[nt][r];
      unsigned short v = f2b(av);
      if (a < 2) {
        unsigned short* dst = (a == 0) ? Qb : Kb;
        dst[((size_t)(h * NT + row)) * DHP + d] = v;
      } else {
        Vtb[((size_t)(h * DVP + d)) * NT + row] = v;
      }
    }
  }
}

// ---------------- kernel 3: masked attention, S^T formulation ----------------
// grid (64 q-tiles of 64 rows, 8 heads, KS splits); block 256 = 4 waves x 16 q-rows.
__global__ __launch_bounds__(256, 6) void attn_kernel(
    const unsigned short* __restrict__ Qb, const unsigned short* __restrict__ Kb,
    const unsigned short* __restrict__ Vtb, const unsigned char* __restrict__ sigb,
    float* __restrict__ Opart, float* __restrict__ Lpart) {
  __shared__ __align__(16) unsigned short kt[64 * KSTR];       // K tile [j][d]  8704 B
  __shared__ __align__(16) unsigned short pt[4][16 * PSTR];    // per-wave P^T   8960 B
  const int t = threadIdx.x;
  const int w = t >> 6, lane = t & 63, quad = lane >> 4, ln = lane & 15;
  const int h = blockIdx.y, qt = blockIdx.x, sp = blockIdx.z;
  const int qrow = qt * 64 + w * 16;
  const int j0 = sp * 16, j1 = j0 + 16;

  const unsigned short* Kh = Kb + (size_t)h * NT * DHP;
  const unsigned short* Vh = Vtb + (size_t)h * DVP * NT;
  unsigned short* ptw = pt[w];

  const int row = qrow + ln;
  const unsigned short* Qp = Qb + ((size_t)h * NT + row) * DHP;
  bf16x8 qa0 = ld_bf8(Qp + quad * 8);        // A[m=ln][k=quad*8+j], k 0..31
  bf16x8 qa1 = ld_bf8(Qp + 32 + quad * 8);   // k 32..63 (K-pads are zero)
  unsigned sq = sigb[row];
  unsigned uq = (sq == 0u) ? 1u : 0u;
  if (uq) {                                  // uniform row: logits exactly 0 -> p = 1
    uint4 z = {0, 0, 0, 0};
    qa0 = __builtin_bit_cast(bf16x8, z);
    qa1 = __builtin_bit_cast(bf16x8, z);
  }
  float rs = 0.f;
  f32x4 o[3] = {{0,0,0,0},{0,0,0,0},{0,0,0,0}};

  const uint4* ks0 = (const uint4*)(Kh + (size_t)j0 * 64 * DHP);
  uint4 kr0 = ks0[t], kr1 = ks0[t + 256];    // register-prefetched K tile

  for (int jt = j0; jt < j1; ++jt) {
    __syncthreads();                          // all waves done reading kt
    *(uint4*)&kt[(t >> 3) * KSTR + (t & 7) * 8] = kr0;
    {
      int idx = t + 256;
      *(uint4*)&kt[(idx >> 3) * KSTR + (idx & 7) * 8] = kr1;
    }
    int jn = (jt + 1 < j1) ? jt + 1 : jt;
    const uint4* ksrc = (const uint4*)(Kh + (size_t)jn * 64 * DHP);
    uint4 nk0 = ksrc[t], nk1 = ksrc[t + 256];  // prefetch next tile
    __syncthreads();                          // kt ready

#pragma unroll
    for (int nt = 0; nt < 4; ++nt) {
      bf16x8 ka0 = ld_bf8(&kt[(nt * 16 + ln) * KSTR + quad * 8]);
      bf16x8 ka1 = ld_bf8(&kt[(nt * 16 + ln) * KSTR + 32 + quad * 8]);
      f32x4 acc = {0.f, 0.f, 0.f, 0.f};
      acc = mfma16(ka0, qa0, acc);            // S^T[j=nt*16+quad*4+r][m=ln]
      acc = mfma16(ka1, qa1, acc);
      unsigned spj = *(const unsigned*)(sigb + jt * 64 + nt * 16 + quad * 4);
      unsigned u[4];
#pragma unroll
      for (int r = 0; r < 4; ++r) {
        unsigned skr = (spj >> (8 * r)) & 255u;
        unsigned msk = (sq & skr) | uq;
        float p = msk ? fexp2(acc[r]) : 0.f;
        unsigned ut = __builtin_bit_cast(unsigned, p) & 0xffff0000u; // trunc to bf16
        rs += __builtin_bit_cast(float, ut);  // denominator == numerator weights
        u[r] = ut;
      }
      unsigned* pw = (unsigned*)&ptw[ln * PSTR + nt * 16 + quad * 4];
      pw[0] = (u[0] >> 16) | u[1];            // bf16 pair (j+0, j+1)
      pw[1] = (u[2] >> 16) | u[3];            // bf16 pair (j+2, j+3)
    }
    // V fragments for this jt straight from global (L2-hot)
    uint4 vf[6];
#pragma unroll
    for (int ot = 0; ot < 3; ++ot) {
      const unsigned short* vp = Vh + (size_t)(ot * 16 + ln) * NT + jt * 64 + quad * 8;
      vf[ot * 2]     = *(const uint4*)vp;
      vf[ot * 2 + 1] = *(const uint4*)(vp + 32);
    }
    asm volatile("s_waitcnt lgkmcnt(0)" ::: "memory");   // wave-private P RAW
    bf16x8 pb0 = ld_bf8(&ptw[ln * PSTR + quad * 8]);
    bf16x8 pb1 = ld_bf8(&ptw[ln * PSTR + 32 + quad * 8]);
#pragma unroll
    for (int ot = 0; ot < 3; ++ot) {
      bf16x8 va0 = __builtin_bit_cast(bf16x8, vf[ot * 2]);
      bf16x8 va1 = __builtin_bit_cast(bf16x8, vf[ot * 2 + 1]);
      o[ot] = mfma16(va0, pb0, o[ot]);        // O^T[d][m]
      o[ot] = mfma16(va1, pb1, o[ot]);
    }
    kr0 = nk0; kr1 = nk1;
  }

  // epilogue: reduce row-sum across quads; store O^T (lane: m=ln, d=quad*4+r+16ot)
  float s = rs;
  s += __shfl_xor(s, 16);
  s += __shfl_xor(s, 32);
  float* Op = Opart + ((size_t)(sp * NH + h) * NT + row) * DH;
#pragma unroll
  for (int ot = 0; ot < 3; ++ot)
#pragma unroll
    for (int r = 0; r < 4; ++r) {
      int d = ot * 16 + quad * 4 + r;
      if (d < DH) Op[d] = o[ot][r];
    }
  if (lane < 16)
    Lpart[(size_t)(sp * NH + h) * NT + row] = s;
}

// ---------------- kernel 3b: split-K combine (vectorized) ----------------
__global__ __launch_bounds__(256) void combine_kernel(
    const float* __restrict__ Opart, const float* __restrict__ Lpart,
    unsigned short* __restrict__ Ob) {
  int idx = blockIdx.x * 256 + threadIdx.x;   // < NT*NH*5
  int row = idx / 40, rem = idx % 40;         // rem = h*5 + dblk
  int h = rem / 5, dblk = rem % 5;
  f32x4 o0 = {0,0,0,0}, o1 = {0,0,0,0};
  float ls = 0.f;
#pragma unroll
  for (int sps = 0; sps < KS; ++sps) {
    const float* p = Opart + ((size_t)(sps * NH + h) * NT + row) * DH + dblk * 8;
    o0 += *(const f32x4*)p;
    o1 += *(const f32x4*)(p + 4);
    ls += Lpart[(size_t)(sps * NH + h) * NT + row];
  }
  float inv = 1.f / ls;
  unsigned short ob[8];
#pragma unroll
  for (int j = 0; j < 4; ++j) { ob[j] = f2b(o0[j] * inv); ob[4 + j] = f2b(o1[j] * inv); }
  *(uint4*)(Ob + (size_t)idx * 8) = *(const uint4*)ob;   // Ob[row][h*40+dblk*8..]
}

// ---------------- kernel 4: output projection + bias (LDS-free) ----------------
__global__ __launch_bounds__(256, 4) void out_gemm(
    const unsigned short* __restrict__ Ob, const unsigned short* __restrict__ Wt,
    const float* __restrict__ bo, float* __restrict__ out) {
  const int t = threadIdx.x;
  const int w = t >> 6, lane = t & 63, quad = lane >> 4, ln = lane & 15;
  const int m0 = blockIdx.x * 64;
  const int cc0 = blockIdx.y * 32;
  const unsigned short* Arow = Ob + (size_t)(m0 + w * 16 + ln) * DM + quad * 8;
  const unsigned short* Brow = Wt + (size_t)(960 + cc0 + ln) * DM + quad * 8;

  f32x4 acc[2] = {{0,0,0,0},{0,0,0,0}};
  for (int kc = 0; kc < 10; ++kc) {
    bf16x8 af = ld_bf8(Arow + kc * 32);
#pragma unroll
    for (int nt = 0; nt < 2; ++nt) {
      bf16x8 bf = ld_bf8(Brow + (size_t)nt * 16 * DM + kc * 32);
      acc[nt] = mfma16(af, bf, acc[nt]);
    }
  }
#pragma unroll
  for (int nt = 0; nt < 2; ++nt)
#pragma unroll
    for (int r = 0; r < 4; ++r) {
      int row = m0 + w * 16 + quad * 4 + r;
      int col = cc0 + nt * 16 + ln;
      out[(size_t)row * DM + col] = acc[nt][r] + bo[col];
    }
}

// ---------------- launcher ----------------
extern "C" void kernel_launch(void* const* d_in, const int* in_sizes, int n_in,
                              void* d_out, int out_size, void* d_ws, size_t ws_size,
                              hipStream_t stream) {
  const float* x  = (const float*)d_in[0];
  const float* g  = (const float*)d_in[1];
  const float* Wq = (const float*)d_in[2];
  const float* Wk = (const float*)d_in[3];
  const float* Wv = (const float*)d_in[4];
  const float* Wo = (const float*)d_in[5];
  const float* bo = (const float*)d_in[6];
  float* out = (float*)d_out;

  char* ws = (char*)d_ws;
  const size_t SIG_OFF = 0;
  const size_t XB_OFF  = 16384;
  const size_t WT_OFF  = XB_OFF + (size_t)NT * DM * 2;              // +2.62 MB
  const size_t QB_OFF  = WT_OFF + (size_t)1280 * DM * 2;            // +0.82 MB
  const size_t KB_OFF  = QB_OFF + (size_t)NH * NT * DHP * 2;        // +4 MiB
  const size_t VT_OFF  = KB_OFF + (size_t)NH * NT * DHP * 2;        // +4 MiB
  const size_t OB_OFF  = VT_OFF + (size_t)NH * DVP * NT * 2;        // +3 MiB
  const size_t OP_OFF  = OB_OFF + (size_t)NT * DM * 2;              // +2.62 MB
  const size_t LP_OFF  = OP_OFF + (size_t)KS * NH * NT * DH * 4;    // +21 MB
  unsigned char* sigb  = (unsigned char*)(ws + SIG_OFF);
  unsigned short* xb   = (unsigned short*)(ws + XB_OFF);
  unsigned short* Wt   = (unsigned short*)(ws + WT_OFF);
  unsigned short* Qb   = (unsigned short*)(ws + QB_OFF);
  unsigned short* Kb   = (unsigned short*)(ws + KB_OFF);
  unsigned short* Vtb  = (unsigned short*)(ws + VT_OFF);
  unsigned short* Ob   = (unsigned short*)(ws + OB_OFF);
  float* Opart         = (float*)(ws + OP_OFF);
  float* Lpart         = (float*)(ws + LP_OFF);

  // Only K pads must be zero (Q-pad garbage multiplies K-pad zeros; V pad rows
  // feed only discarded output rows d=40..47; 0xAA poison is never NaN in bf16).
  hipMemsetAsync(ws + KB_OFF, 0, (size_t)NH * NT * DHP * 2, stream);

  sig_kernel<<<16, 256, 0, stream>>>(g, sigb);
  cvt_x<<<(NT * DM) / 1024, 256, 0, stream>>>(x, xb);
  cvt_w<<<dim3(5, 20), 256, 0, stream>>>(Wq, Wk, Wv, Wo, Wt);
  qkv_gemm<<<dim3(64, 15), 256, 0, stream>>>(xb, Wt, Qb, Kb, Vtb);
  attn_kernel<<<dim3(64, NH, KS), 256, 0, stream>>>(Qb, Kb, Vtb, sigb, Opart, Lpart);
  combine_kernel<<<(NT * NH * 5) / 256, 256, 0, stream>>>(Opart, Lpart, Ob);
  out_gemm<<<dim3(64, 10), 256, 0, stream>>>(Ob, Wt, bo, out);
}

// Round 6
// 235.086 us; speedup vs baseline: 1.2306x; 1.2306x over previous
//
#include <hip/hip_runtime.h>
#include <hip/hip_bf16.h>
#include <stdint.h>

// Problem constants
#define NT 4096      // tokens
#define DM 320       // model dim
#define NH 8         // heads
#define DH 40        // head dim
#define DHP 64       // padded head dim for Q/K (K pads zeroed; MFMA K=32 x2)
#define DVP 48       // padded head dim rows for V^T (rows 40..47 garbage, discarded)
#define KS 8         // split-K factor over the key dimension
#define QSCALE 0.22811013f  // (1/sqrt(40)) * log2(e): folded into Q so p = exp2(qk)
#define KSTR 68      // K-tile LDS row stride (ushorts): 34 dwords == 2 mod 32 -> <=2-way
#define PSTR 68      // P-tile LDS row stride: 136B rows keep b64 writes 8B-aligned

typedef float f32x4 __attribute__((ext_vector_type(4)));
typedef __bf16 bf16x8 __attribute__((ext_vector_type(8)));

__device__ __forceinline__ unsigned short f2b(float f) {
  unsigned u = __builtin_bit_cast(unsigned, f);
  u += 0x7FFFu + ((u >> 16) & 1u);   // RNE
  return (unsigned short)(u >> 16);
}

__device__ __forceinline__ bf16x8 ld_bf8(const unsigned short* p) {
  uint4 v = *(const uint4*)p;        // 16B load
  return __builtin_bit_cast(bf16x8, v);
}

__device__ __forceinline__ f32x4 mfma16(bf16x8 a, bf16x8 b, f32x4 c) {
  return __builtin_amdgcn_mfma_f32_16x16x32_bf16(a, b, c, 0, 0, 0);
}

__device__ __forceinline__ float fexp2(float x) {
#if __has_builtin(__builtin_amdgcn_exp2f)
  return __builtin_amdgcn_exp2f(x);
#else
  float r; asm("v_exp_f32 %0, %1" : "=v"(r) : "v"(x)); return r;
#endif
}

// ---------------- kernel 1: fused prep (cvt_x | sig | cvt_w) ----------------
// blocks 0..1279: x->bf16; 1280..1295: signatures; 1296..1395: weights->bf16^T.
// Wt[1280][320]: rows 0..319 Wq^T, 320..639 Wk^T, 640..959 Wv^T, 960..1279 Wo^T.
__global__ __launch_bounds__(256) void prep_kernel(
    const float* __restrict__ x, const float* __restrict__ g,
    const float* __restrict__ Wq, const float* __restrict__ Wk,
    const float* __restrict__ Wv, const float* __restrict__ Wo,
    unsigned short* __restrict__ xb, unsigned char* __restrict__ sigb,
    unsigned short* __restrict__ Wt) {
  __shared__ __align__(16) unsigned short lt[64 * 72];
  const int b = blockIdx.x, t = threadIdx.x;
  if (b < 1280) {                       // ---- x -> bf16
    int i = (b * 256 + t) * 4;
    float4 v = *(const float4*)(x + i);
    ushort4 u;
    u.x = f2b(v.x); u.y = f2b(v.y); u.z = f2b(v.z); u.w = f2b(v.w);
    *(ushort4*)(xb + i) = u;
  } else if (b < 1296) {                // ---- phase signatures
    int i = (b - 1280) * 256 + t;
    unsigned s = 0;
    if (g[i] != 0.f)          s |= 1u;
    if (g[NT + i] != 0.f)     s |= 2u;
    if (g[2 * NT + i] != 0.f) s |= 4u;
    sigb[i] = (unsigned char)s;
  } else {                              // ---- weights -> bf16 transposed
    int bb = b - 1296;                  // 0..99
    int kx = bb % 5, cy = bb / 5;       // kx: k-tile, cy: c-tile over 4 mats
    int cm = cy % 5;
    const float* src;
    int rowbase;
    if (cy < 5)       { src = Wq; rowbase = cm * 64; }
    else if (cy < 10) { src = Wk; rowbase = 320 + cm * 64; }
    else if (cy < 15) { src = Wv; rowbase = 640 + cm * 64; }
    else              { src = Wo; rowbase = 960 + cm * 64; }
    const int c0 = cm * 64;
    const int k0 = kx * 64;
#pragma unroll
    for (int i = 0; i < 4; ++i) {       // read 64k x 64c fp32, transpose to LDS
      int kr = (t >> 4) + i * 16, cc = (t & 15) * 4;
      float4 w4 = *(const float4*)&src[(size_t)(k0 + kr) * DM + c0 + cc];
      lt[(cc + 0) * 72 + kr] = f2b(w4.x);
      lt[(cc + 1) * 72 + kr] = f2b(w4.y);
      lt[(cc + 2) * 72 + kr] = f2b(w4.z);
      lt[(cc + 3) * 72 + kr] = f2b(w4.w);
    }
    __syncthreads();
#pragma unroll
    for (int i = 0; i < 2; ++i) {       // write 64c rows, k-contiguous
      int idx = t + i * 256, cl = idx >> 3, ch = idx & 7;
      *(uint4*)&Wt[(size_t)(rowbase + cl) * DM + k0 + ch * 8] =
          *(const uint4*)&lt[cl * 72 + ch * 8];
    }
  }
}

// ---------------- kernel 2: fused QKV projection (LDS-free, frags from L2) ----------------
__global__ __launch_bounds__(256, 4) void qkv_gemm(
    const unsigned short* __restrict__ xb, const unsigned short* __restrict__ Wt,
    unsigned short* __restrict__ Qb, unsigned short* __restrict__ Kb,
    unsigned short* __restrict__ Vtb) {
  const int t = threadIdx.x;
  const int w = t >> 6, lane = t & 63, quad = lane >> 4, ln = lane & 15;
  const int m0 = blockIdx.x * 64;
  const int cy = blockIdx.y;                  // 0..14
  const int a = cy / 5;                       // 0=Q 1=K 2=V
  const int cc0 = (cy % 5) * 64;
  const unsigned short* Arow = xb + (size_t)(m0 + w * 16 + ln) * DM + quad * 8;
  const unsigned short* Brow = Wt + (size_t)(a * 320 + cc0 + ln) * DM + quad * 8;

  f32x4 acc[4] = {{0,0,0,0},{0,0,0,0},{0,0,0,0},{0,0,0,0}};
  for (int kc = 0; kc < 10; ++kc) {
    bf16x8 af = ld_bf8(Arow + kc * 32);
#pragma unroll
    for (int nt = 0; nt < 4; ++nt) {
      bf16x8 bf = ld_bf8(Brow + (size_t)nt * 16 * DM + kc * 32);
      acc[nt] = mfma16(af, bf, acc[nt]);
    }
  }
#pragma unroll
  for (int nt = 0; nt < 4; ++nt) {
#pragma unroll
    for (int r = 0; r < 4; ++r) {
      int row = m0 + w * 16 + quad * 4 + r;   // D row = quad*4+reg
      int cc = cc0 + nt * 16 + ln;            // D col = lane&15
      int h = cc / DH, d = cc % DH;
      float av = (a == 0) ? acc[nt][r] * QSCALE : acc[nt][r];
      unsigned short v = f2b(av);
      if (a < 2) {
        unsigned short* dst = (a == 0) ? Qb : Kb;
        dst[((size_t)(h * NT + row)) * DHP + d] = v;
      } else {
        Vtb[((size_t)(h * DVP + d)) * NT + row] = v;
      }
    }
  }
}

// ---------------- kernel 3: masked attention, S^T formulation ----------------
// grid (32 q-tiles of 128 rows, 8 heads, KS=8 splits); block 256 = 4 waves x 32 q-rows.
// S^T = K*Q^T (A=K, B=Q): lane holds 4 consecutive j for a fixed query m=ln;
// P packed bf16, b64 LDS writes; PV: O^T = V^T * P (V frags straight from L2).
__global__ __launch_bounds__(256, 4) void attn_kernel(
    const unsigned short* __restrict__ Qb, const unsigned short* __restrict__ Kb,
    const unsigned short* __restrict__ Vtb, const unsigned char* __restrict__ sigb,
    unsigned short* __restrict__ Opart, float* __restrict__ Lpart) {
  __shared__ __align__(16) unsigned short kt[64 * KSTR];       // K tile [j][d]   8704 B
  __shared__ __align__(16) unsigned short pt[4][32 * PSTR];    // per-wave P^T   17408 B
  const int t = threadIdx.x;
  const int w = t >> 6, lane = t & 63, quad = lane >> 4, ln = lane & 15;
  const int h = blockIdx.y, qt = blockIdx.x, sp = blockIdx.z;
  const int qrow = qt * 128 + w * 32;
  const int j0 = sp * 8, j1 = j0 + 8;

  const unsigned short* Kh = Kb + (size_t)h * NT * DHP;
  const unsigned short* Vh = Vtb + (size_t)h * DVP * NT;
  unsigned short* ptw = pt[w];

  bf16x8 qa[2][2];
  unsigned sq[2], uq[2];
  float rs[2] = {0.f, 0.f};
  f32x4 o[3][2] = {{{0,0,0,0},{0,0,0,0}},{{0,0,0,0},{0,0,0,0}},{{0,0,0,0},{0,0,0,0}}};

#pragma unroll
  for (int tq = 0; tq < 2; ++tq) {
    int row = qrow + tq * 16 + ln;
    const unsigned short* Qp = Qb + ((size_t)h * NT + row) * DHP;
    qa[tq][0] = ld_bf8(Qp + quad * 8);
    qa[tq][1] = ld_bf8(Qp + 32 + quad * 8);
    unsigned s = sigb[row];
    sq[tq] = s;
    uq[tq] = (s == 0u) ? 1u : 0u;
    if (s == 0u) {                 // uniform row: logits exactly 0 -> p = 1
      uint4 z = {0, 0, 0, 0};
      qa[tq][0] = __builtin_bit_cast(bf16x8, z);
      qa[tq][1] = __builtin_bit_cast(bf16x8, z);
    }
  }

  const uint4* ks0 = (const uint4*)(Kh + (size_t)j0 * 64 * DHP);
  uint4 kr0 = ks0[t], kr1 = ks0[t + 256];    // register-prefetched K tile

  for (int jt = j0; jt < j1; ++jt) {
    __syncthreads();                          // all waves done reading kt
    *(uint4*)&kt[(t >> 3) * KSTR + (t & 7) * 8] = kr0;
    {
      int idx = t + 256;
      *(uint4*)&kt[(idx >> 3) * KSTR + (idx & 7) * 8] = kr1;
    }
    int jn = (jt + 1 < j1) ? jt + 1 : jt;
    const uint4* ksrc = (const uint4*)(Kh + (size_t)jn * 64 * DHP);
    uint4 nk0 = ksrc[t], nk1 = ksrc[t + 256];  // prefetch next tile
    __syncthreads();                          // kt ready

    // V fragments for this jt straight from global (L2-hot), shared by both tq
    uint4 vf[6];
#pragma unroll
    for (int ot = 0; ot < 3; ++ot) {
      const unsigned short* vp = Vh + (size_t)(ot * 16 + ln) * NT + jt * 64 + quad * 8;
      vf[ot * 2]     = *(const uint4*)vp;
      vf[ot * 2 + 1] = *(const uint4*)(vp + 32);
    }

#pragma unroll
    for (int nt = 0; nt < 4; ++nt) {
      bf16x8 ka0 = ld_bf8(&kt[(nt * 16 + ln) * KSTR + quad * 8]);
      bf16x8 ka1 = ld_bf8(&kt[(nt * 16 + ln) * KSTR + 32 + quad * 8]);
      unsigned spj = *(const unsigned*)(sigb + jt * 64 + nt * 16 + quad * 4);
#pragma unroll
      for (int tq = 0; tq < 2; ++tq) {
        f32x4 acc = {0.f, 0.f, 0.f, 0.f};
        acc = mfma16(ka0, qa[tq][0], acc);    // S^T[j=nt*16+quad*4+r][m=ln]
        acc = mfma16(ka1, qa[tq][1], acc);
        unsigned u[4];
#pragma unroll
        for (int r = 0; r < 4; ++r) {
          unsigned skr = (spj >> (8 * r)) & 255u;
          unsigned msk = (sq[tq] & skr) | uq[tq];
          float p = msk ? fexp2(acc[r]) : 0.f;
          unsigned ut = __builtin_bit_cast(unsigned, p) & 0xffff0000u; // trunc to bf16
          rs[tq] += __builtin_bit_cast(float, ut);  // denom == numerator weights
          u[r] = ut;
        }
        uint2 pk;
        pk.x = (u[0] >> 16) | u[1];           // bf16 pair (j+0, j+1)
        pk.y = (u[2] >> 16) | u[3];           // bf16 pair (j+2, j+3)
        *(uint2*)&ptw[(tq * 16 + ln) * PSTR + nt * 16 + quad * 4] = pk;  // b64
      }
    }
    asm volatile("s_waitcnt lgkmcnt(0)" ::: "memory");   // wave-private P RAW
    bf16x8 pb[2][2];
#pragma unroll
    for (int tq = 0; tq < 2; ++tq) {
      pb[tq][0] = ld_bf8(&ptw[(tq * 16 + ln) * PSTR + quad * 8]);
      pb[tq][1] = ld_bf8(&ptw[(tq * 16 + ln) * PSTR + 32 + quad * 8]);
    }
#pragma unroll
    for (int ot = 0; ot < 3; ++ot) {
      bf16x8 va0 = __builtin_bit_cast(bf16x8, vf[ot * 2]);
      bf16x8 va1 = __builtin_bit_cast(bf16x8, vf[ot * 2 + 1]);
#pragma unroll
      for (int tq = 0; tq < 2; ++tq) {
        o[ot][tq] = mfma16(va0, pb[tq][0], o[ot][tq]);   // O^T[d][m]
        o[ot][tq] = mfma16(va1, pb[tq][1], o[ot][tq]);
      }
    }
    kr0 = nk0; kr1 = nk1;
  }

  // epilogue: reduce row-sum across quads; store O^T partials as bf16
#pragma unroll
  for (int tq = 0; tq < 2; ++tq) {
    float s = rs[tq];
    s += __shfl_xor(s, 16);
    s += __shfl_xor(s, 32);
    int row = qrow + tq * 16 + ln;
    unsigned short* Op = Opart + ((size_t)(sp * NH + h) * NT + row) * DH;
#pragma unroll
    for (int ot = 0; ot < 3; ++ot) {
      int d0 = ot * 16 + quad * 4;
      if (d0 < DH) {
        uint2 pk;
        pk.x = (unsigned)f2b(o[ot][tq][0]) | ((unsigned)f2b(o[ot][tq][1]) << 16);
        pk.y = (unsigned)f2b(o[ot][tq][2]) | ((unsigned)f2b(o[ot][tq][3]) << 16);
        *(uint2*)(Op + d0) = pk;
      }
    }
    if (lane < 16)
      Lpart[(size_t)(sp * NH + h) * NT + row] = s;
  }
}

// ---------------- kernel 3b: split-K combine (bf16 partials) ----------------
__global__ __launch_bounds__(256) void combine_kernel(
    const unsigned short* __restrict__ Opart, const float* __restrict__ Lpart,
    unsigned short* __restrict__ Ob) {
  int idx = blockIdx.x * 256 + threadIdx.x;   // < NT*NH*5
  int row = idx / 40, rem = idx % 40;         // rem = h*5 + dblk
  int h = rem / 5, dblk = rem % 5;
  float os[8] = {0,0,0,0,0,0,0,0};
  float ls = 0.f;
#pragma unroll
  for (int sps = 0; sps < KS; ++sps) {
    const unsigned short* p = Opart + ((size_t)(sps * NH + h) * NT + row) * DH + dblk * 8;
    uint4 v = *(const uint4*)p;
    unsigned vv[4] = {v.x, v.y, v.z, v.w};
#pragma unroll
    for (int j = 0; j < 4; ++j) {
      os[2 * j]     += __builtin_bit_cast(float, vv[j] << 16);
      os[2 * j + 1] += __builtin_bit_cast(float, vv[j] & 0xffff0000u);
    }
    ls += Lpart[(size_t)(sps * NH + h) * NT + row];
  }
  float inv = 1.f / ls;
  unsigned short ob[8];
#pragma unroll
  for (int j = 0; j < 8; ++j) ob[j] = f2b(os[j] * inv);
  *(uint4*)(Ob + (size_t)idx * 8) = *(const uint4*)ob;   // Ob[row][h*40+dblk*8..]
}

// ---------------- kernel 4: output projection + bias (LDS-free) ----------------
__global__ __launch_bounds__(256, 4) void out_gemm(
    const unsigned short* __restrict__ Ob, const unsigned short* __restrict__ Wt,
    const float* __restrict__ bo, float* __restrict__ out) {
  const int t = threadIdx.x;
  const int w = t >> 6, lane = t & 63, quad = lane >> 4, ln = lane & 15;
  const int m0 = blockIdx.x * 64;
  const int cc0 = blockIdx.y * 32;
  const unsigned short* Arow = Ob + (size_t)(m0 + w * 16 + ln) * DM + quad * 8;
  const unsigned short* Brow = Wt + (size_t)(960 + cc0 + ln) * DM + quad * 8;

  f32x4 acc[2] = {{0,0,0,0},{0,0,0,0}};
  for (int kc = 0; kc < 10; ++kc) {
    bf16x8 af = ld_bf8(Arow + kc * 32);
#pragma unroll
    for (int nt = 0; nt < 2; ++nt) {
      bf16x8 bf = ld_bf8(Brow + (size_t)nt * 16 * DM + kc * 32);
      acc[nt] = mfma16(af, bf, acc[nt]);
    }
  }
#pragma unroll
  for (int nt = 0; nt < 2; ++nt)
#pragma unroll
    for (int r = 0; r < 4; ++r) {
      int row = m0 + w * 16 + quad * 4 + r;
      int col = cc0 + nt * 16 + ln;
      out[(size_t)row * DM + col] = acc[nt][r] + bo[col];
    }
}

// ---------------- launcher ----------------
extern "C" void kernel_launch(void* const* d_in, const int* in_sizes, int n_in,
                              void* d_out, int out_size, void* d_ws, size_t ws_size,
                              hipStream_t stream) {
  const float* x  = (const float*)d_in[0];
  const float* g  = (const float*)d_in[1];
  const float* Wq = (const float*)d_in[2];
  const float* Wk = (const float*)d_in[3];
  const float* Wv = (const float*)d_in[4];
  const float* Wo = (const float*)d_in[5];
  const float* bo = (const float*)d_in[6];
  float* out = (float*)d_out;

  char* ws = (char*)d_ws;
  const size_t SIG_OFF = 0;
  const size_t XB_OFF  = 16384;
  const size_t WT_OFF  = XB_OFF + (size_t)NT * DM * 2;              // +2.62 MB
  const size_t QB_OFF  = WT_OFF + (size_t)1280 * DM * 2;            // +0.82 MB
  const size_t KB_OFF  = QB_OFF + (size_t)NH * NT * DHP * 2;        // +4 MiB
  const size_t VT_OFF  = KB_OFF + (size_t)NH * NT * DHP * 2;        // +4 MiB
  const size_t OB_OFF  = VT_OFF + (size_t)NH * DVP * NT * 2;        // +3 MiB
  const size_t OP_OFF  = OB_OFF + (size_t)NT * DM * 2;              // +2.62 MB
  const size_t LP_OFF  = OP_OFF + (size_t)KS * NH * NT * DH * 2;    // +21 MB (bf16)
  unsigned char* sigb  = (unsigned char*)(ws + SIG_OFF);
  unsigned short* xb   = (unsigned short*)(ws + XB_OFF);
  unsigned short* Wt   = (unsigned short*)(ws + WT_OFF);
  unsigned short* Qb   = (unsigned short*)(ws + QB_OFF);
  unsigned short* Kb   = (unsigned short*)(ws + KB_OFF);
  unsigned short* Vtb  = (unsigned short*)(ws + VT_OFF);
  unsigned short* Ob   = (unsigned short*)(ws + OB_OFF);
  unsigned short* Opart= (unsigned short*)(ws + OP_OFF);
  float* Lpart         = (float*)(ws + LP_OFF);

  // Only K pads must be zero (Q-pad garbage multiplies K-pad zeros; V pad rows
  // feed only discarded output rows d=40..47; 0xAA poison is never NaN in bf16).
  hipMemsetAsync(ws + KB_OFF, 0, (size_t)NH * NT * DHP * 2, stream);

  prep_kernel<<<1396, 256, 0, stream>>>(x, g, Wq, Wk, Wv, Wo, xb, sigb, Wt);
  qkv_gemm<<<dim3(64, 15), 256, 0, stream>>>(xb, Wt, Qb, Kb, Vtb);
  attn_kernel<<<dim3(32, NH, KS), 256, 0, stream>>>(Qb, Kb, Vtb, sigb, Opart, Lpart);
  combine_kernel<<<(NT * NH * 5) / 256, 256, 0, stream>>>(Opart, Lpart, Ob);
  out_gemm<<<dim3(64, 10), 256, 0, stream>>>(Ob, Wt, bo, out);
}

// Round 7
// 179.164 us; speedup vs baseline: 1.6148x; 1.3121x over previous
//
#include <hip/hip_runtime.h>
#include <hip/hip_bf16.h>
#include <stdint.h>

// Problem constants
#define NT 4096      // tokens
#define DM 320       // model dim
#define NH 8         // heads
#define DH 40        // head dim
#define DHP 64       // padded head dim for Q/K (K pads zeroed; MFMA K=32 x2)
#define KS 4         // split-K factor over the key dimension
#define QSCALE 0.22811013f  // (1/sqrt(40)) * log2(e): folded into Q so p = exp2(qk)
#define PSTR 68      // P-tile LDS row stride (ushorts): b64 8B-aligned, <=2-way banks

typedef float f32x4 __attribute__((ext_vector_type(4)));
typedef __bf16 bf16x8 __attribute__((ext_vector_type(8)));

__device__ __forceinline__ unsigned short f2b(float f) {
  unsigned u = __builtin_bit_cast(unsigned, f);
  u += 0x7FFFu + ((u >> 16) & 1u);   // RNE
  return (unsigned short)(u >> 16);
}

__device__ __forceinline__ bf16x8 ld_bf8(const unsigned short* p) {
  uint4 v = *(const uint4*)p;        // 16B load
  return __builtin_bit_cast(bf16x8, v);
}

__device__ __forceinline__ f32x4 mfma16(bf16x8 a, bf16x8 b, f32x4 c) {
  return __builtin_amdgcn_mfma_f32_16x16x32_bf16(a, b, c, 0, 0, 0);
}

__device__ __forceinline__ float fexp2(float x) {
#if __has_builtin(__builtin_amdgcn_exp2f)
  return __builtin_amdgcn_exp2f(x);
#else
  float r; asm("v_exp_f32 %0, %1" : "=v"(r) : "v"(x)); return r;
#endif
}

// ---------------- kernel 1: prep (weights->bf16^T | signatures) ----------------
// blocks 0..99: weight transpose; 100..115: signatures.
// Wt[1280][320]: rows 0..319 Wq^T, 320..639 Wk^T, 640..959 Wv^T, 960..1279 Wo^T.
__global__ __launch_bounds__(256) void prep_kernel(
    const float* __restrict__ g,
    const float* __restrict__ Wq, const float* __restrict__ Wk,
    const float* __restrict__ Wv, const float* __restrict__ Wo,
    unsigned char* __restrict__ sigb, unsigned short* __restrict__ Wt) {
  __shared__ __align__(16) unsigned short lt[64 * 72];
  const int b = blockIdx.x, t = threadIdx.x;
  if (b >= 100) {                       // ---- phase signatures
    int i = (b - 100) * 256 + t;
    unsigned s = 0;
    if (g[i] != 0.f)          s |= 1u;
    if (g[NT + i] != 0.f)     s |= 2u;
    if (g[2 * NT + i] != 0.f) s |= 4u;
    sigb[i] = (unsigned char)s;
    return;
  }
  // ---- weights -> bf16 transposed
  int kx = b % 5, cy = b / 5;           // kx: k-tile, cy: c-tile over 4 mats
  int cm = cy % 5;
  const float* src;
  int rowbase;
  if (cy < 5)       { src = Wq; rowbase = cm * 64; }
  else if (cy < 10) { src = Wk; rowbase = 320 + cm * 64; }
  else if (cy < 15) { src = Wv; rowbase = 640 + cm * 64; }
  else              { src = Wo; rowbase = 960 + cm * 64; }
  const int c0 = cm * 64;
  const int k0 = kx * 64;
#pragma unroll
  for (int i = 0; i < 4; ++i) {         // read 64k x 64c fp32, transpose to LDS
    int kr = (t >> 4) + i * 16, cc = (t & 15) * 4;
    float4 w4 = *(const float4*)&src[(size_t)(k0 + kr) * DM + c0 + cc];
    lt[(cc + 0) * 72 + kr] = f2b(w4.x);
    lt[(cc + 1) * 72 + kr] = f2b(w4.y);
    lt[(cc + 2) * 72 + kr] = f2b(w4.z);
    lt[(cc + 3) * 72 + kr] = f2b(w4.w);
  }
  __syncthreads();
#pragma unroll
  for (int i = 0; i < 2; ++i) {         // write 64c rows, k-contiguous
    int idx = t + i * 256, cl = idx >> 3, ch = idx & 7;
    *(uint4*)&Wt[(size_t)(rowbase + cl) * DM + k0 + ch * 8] =
        *(const uint4*)&lt[cl * 72 + ch * 8];
  }
}

// ---------------- kernel 2: fused QKV projection (LDS-free; x fp32 inline cvt) ----
// Q: [h][n][64] bf16, pre-scaled by QSCALE (d 40..63 garbage, harmless vs K zeros).
// Kf: fragment-major [h][jb=n/16][c=k/32][quad][ln=n%16][e=8] — wave loads 1KB contig.
// Vf: fragment-major [h][jt=n/64][ot=d/16][c][quad][ln=d%16][e] for PV A-frags.
__global__ __launch_bounds__(256, 4) void qkv_gemm(
    const float* __restrict__ x, const unsigned short* __restrict__ Wt,
    unsigned short* __restrict__ Qb, unsigned short* __restrict__ Kf,
    unsigned short* __restrict__ Vf) {
  const int t = threadIdx.x;
  const int w = t >> 6, lane = t & 63, quad = lane >> 4, ln = lane & 15;
  const int m0 = blockIdx.x * 64;
  const int cy = blockIdx.y;                  // 0..14
  const int a = cy / 5;                       // 0=Q 1=K 2=V
  const int cc0 = (cy % 5) * 64;
  const float* Arow = x + (size_t)(m0 + w * 16 + ln) * DM + quad * 8;
  const unsigned short* Brow = Wt + (size_t)(a * 320 + cc0 + ln) * DM + quad * 8;

  f32x4 acc[4] = {{0,0,0,0},{0,0,0,0},{0,0,0,0},{0,0,0,0}};
  for (int kc = 0; kc < 10; ++kc) {
    float4 a0 = *(const float4*)(Arow + kc * 32);
    float4 a1 = *(const float4*)(Arow + kc * 32 + 4);
    unsigned short af8[8];
    af8[0] = f2b(a0.x); af8[1] = f2b(a0.y); af8[2] = f2b(a0.z); af8[3] = f2b(a0.w);
    af8[4] = f2b(a1.x); af8[5] = f2b(a1.y); af8[6] = f2b(a1.z); af8[7] = f2b(a1.w);
    bf16x8 af = ld_bf8(af8);
#pragma unroll
    for (int nt = 0; nt < 4; ++nt) {
      bf16x8 bf = ld_bf8(Brow + (size_t)nt * 16 * DM + kc * 32);
      acc[nt] = mfma16(af, bf, acc[nt]);
    }
  }
#pragma unroll
  for (int nt = 0; nt < 4; ++nt) {
#pragma unroll
    for (int r = 0; r < 4; ++r) {
      int row = m0 + w * 16 + quad * 4 + r;   // D row = quad*4+reg
      int cc = cc0 + nt * 16 + ln;            // D col = lane&15
      int h = cc / DH, d = cc % DH;
      if (a == 0) {
        Qb[((size_t)(h * NT + row)) * DHP + d] = f2b(acc[nt][r] * QSCALE);
      } else if (a == 1) {
        size_t idx = ((((size_t)(h * 256 + (row >> 4)) * 2 + (d >> 5)) * 4 +
                       ((d >> 3) & 3)) * 16 + (row & 15)) * 8 + (d & 7);
        Kf[idx] = f2b(acc[nt][r]);
      } else {
        size_t idx = (((((size_t)(h * 64 + (row >> 6)) * 3 + (d >> 4)) * 2 +
                        ((row >> 5) & 1)) * 4 + ((row >> 3) & 3)) * 16 +
                      (d & 15)) * 8 + (row & 7);
        Vf[idx] = f2b(acc[nt][r]);
      }
    }
  }
}

// ---------------- kernel 3: barrier-free masked attention ----------------
// grid (32 q-tiles of 128 rows, 8 heads, KS=4); block 256 = 4 waves x 32 q-rows.
// S^T = K*Q^T (A=K frags from Kf, perfectly coalesced); P via wave-private LDS;
// O^T = V^T*P (A=V frags from Vf). NO __syncthreads anywhere.
__global__ __launch_bounds__(256, 4) void attn_kernel(
    const unsigned short* __restrict__ Qb, const unsigned short* __restrict__ Kf,
    const unsigned short* __restrict__ Vf, const unsigned char* __restrict__ sigb,
    unsigned short* __restrict__ Opart, float* __restrict__ Lpart) {
  __shared__ __align__(16) unsigned short pt[4][32 * PSTR];   // per-wave P^T 17408 B
  const int t = threadIdx.x;
  const int w = t >> 6, lane = t & 63, quad = lane >> 4, ln = lane & 15;
  const int h = blockIdx.y, qt = blockIdx.x, sp = blockIdx.z;
  const int qrow = qt * 128 + w * 32;
  const int j0 = sp * 16;

  const unsigned short* Kfh = Kf + (size_t)h * 262144;   // 256 jb * 2c * 512
  const unsigned short* Vfh = Vf + (size_t)h * 196608;   // 64 jt * 3ot * 2c * 512
  unsigned short* ptw = pt[w];

  bf16x8 qa[2][2];
  unsigned sq[2], uq[2];
  float rs[2] = {0.f, 0.f};
  f32x4 o[3][2] = {{{0,0,0,0},{0,0,0,0}},{{0,0,0,0},{0,0,0,0}},{{0,0,0,0},{0,0,0,0}}};

#pragma unroll
  for (int tq = 0; tq < 2; ++tq) {
    int row = qrow + tq * 16 + ln;
    const unsigned short* Qp = Qb + ((size_t)h * NT + row) * DHP;
    qa[tq][0] = ld_bf8(Qp + quad * 8);
    qa[tq][1] = ld_bf8(Qp + 32 + quad * 8);
    unsigned s = sigb[row];
    sq[tq] = s;
    uq[tq] = (s == 0u) ? 1u : 0u;
    if (s == 0u) {                 // uniform row: logits exactly 0 -> p = 1
      uint4 z = {0, 0, 0, 0};
      qa[tq][0] = __builtin_bit_cast(bf16x8, z);
      qa[tq][1] = __builtin_bit_cast(bf16x8, z);
    }
  }

  for (int jt = j0; jt < j0 + 16; ++jt) {
    // K fragments: 8 coalesced 1KB wave loads straight from L2
    uint4 kfr[8];
#pragma unroll
    for (int nt = 0; nt < 4; ++nt)
#pragma unroll
      for (int c = 0; c < 2; ++c)
        kfr[nt * 2 + c] =
            *(const uint4*)(Kfh + ((size_t)((jt * 4 + nt) * 2 + c)) * 512 + lane * 8);

#pragma unroll
    for (int nt = 0; nt < 4; ++nt) {
      bf16x8 ka0 = __builtin_bit_cast(bf16x8, kfr[nt * 2]);
      bf16x8 ka1 = __builtin_bit_cast(bf16x8, kfr[nt * 2 + 1]);
      unsigned spj = *(const unsigned*)(sigb + jt * 64 + nt * 16 + quad * 4);
#pragma unroll
      for (int tq = 0; tq < 2; ++tq) {
        f32x4 acc = {0.f, 0.f, 0.f, 0.f};
        acc = mfma16(ka0, qa[tq][0], acc);    // S^T[j=nt*16+quad*4+r][m=ln]
        acc = mfma16(ka1, qa[tq][1], acc);
        unsigned u[4];
#pragma unroll
        for (int r = 0; r < 4; ++r) {
          unsigned skr = (spj >> (8 * r)) & 255u;
          unsigned msk = (sq[tq] & skr) | uq[tq];
          float p = msk ? fexp2(acc[r]) : 0.f;
          unsigned ut = __builtin_bit_cast(unsigned, p) & 0xffff0000u; // trunc bf16
          rs[tq] += __builtin_bit_cast(float, ut);  // denom == numerator weights
          u[r] = ut;
        }
        uint2 pk;
        pk.x = (u[0] >> 16) | u[1];           // bf16 pair (j+0, j+1)
        pk.y = (u[2] >> 16) | u[3];           // bf16 pair (j+2, j+3)
        *(uint2*)&ptw[(tq * 16 + ln) * PSTR + nt * 16 + quad * 4] = pk;  // b64
      }
    }
    // V fragments: 6 coalesced 1KB wave loads (consumed after P round-trip)
    uint4 vfr[6];
#pragma unroll
    for (int ot = 0; ot < 3; ++ot)
#pragma unroll
      for (int c = 0; c < 2; ++c)
        vfr[ot * 2 + c] =
            *(const uint4*)(Vfh + ((size_t)((jt * 3 + ot) * 2 + c)) * 512 + lane * 8);

    asm volatile("s_waitcnt lgkmcnt(0)" ::: "memory");   // wave-private P RAW
    bf16x8 pb[2][2];
#pragma unroll
    for (int tq = 0; tq < 2; ++tq) {
      pb[tq][0] = ld_bf8(&ptw[(tq * 16 + ln) * PSTR + quad * 8]);
      pb[tq][1] = ld_bf8(&ptw[(tq * 16 + ln) * PSTR + 32 + quad * 8]);
    }
#pragma unroll
    for (int ot = 0; ot < 3; ++ot) {
      bf16x8 va0 = __builtin_bit_cast(bf16x8, vfr[ot * 2]);
      bf16x8 va1 = __builtin_bit_cast(bf16x8, vfr[ot * 2 + 1]);
#pragma unroll
      for (int tq = 0; tq < 2; ++tq) {
        o[ot][tq] = mfma16(va0, pb[tq][0], o[ot][tq]);   // O^T[d][m]
        o[ot][tq] = mfma16(va1, pb[tq][1], o[ot][tq]);
      }
    }
  }

  // epilogue: reduce row-sum across quads; store bf16 partials [sp][row][DM]
#pragma unroll
  for (int tq = 0; tq < 2; ++tq) {
    float s = rs[tq];
    s += __shfl_xor(s, 16);
    s += __shfl_xor(s, 32);
    int row = qrow + tq * 16 + ln;
    unsigned short* Op = Opart + (size_t)(sp * NT + row) * DM + h * DH;
#pragma unroll
    for (int ot = 0; ot < 3; ++ot) {
      int d0 = ot * 16 + quad * 4;
      if (d0 < DH) {
        uint2 pk;
        pk.x = (unsigned)f2b(o[ot][tq][0]) | ((unsigned)f2b(o[ot][tq][1]) << 16);
        pk.y = (unsigned)f2b(o[ot][tq][2]) | ((unsigned)f2b(o[ot][tq][3]) << 16);
        *(uint2*)(Op + d0) = pk;
      }
    }
    if (lane < 16)
      Lpart[sp * NT + row] = s;
  }
}

// ---------------- kernel 4: out projection + split-K combine + bias ----------------
__global__ __launch_bounds__(256, 4) void out_gemm(
    const unsigned short* __restrict__ Opart, const float* __restrict__ Lpart,
    const unsigned short* __restrict__ Wt, const float* __restrict__ bo,
    float* __restrict__ out) {
  const int t = threadIdx.x;
  const int w = t >> 6, lane = t & 63, quad = lane >> 4, ln = lane & 15;
  const int m0 = blockIdx.x * 64;
  const int cc0 = blockIdx.y * 32;
  const int arow = m0 + w * 16 + ln;
  float ls = 0.f;
#pragma unroll
  for (int sp = 0; sp < KS; ++sp) ls += Lpart[sp * NT + arow];
  const float inv = 1.f / ls;
  const unsigned short* Brow = Wt + (size_t)(960 + cc0 + ln) * DM + quad * 8;

  f32x4 acc[2] = {{0,0,0,0},{0,0,0,0}};
  for (int kc = 0; kc < 10; ++kc) {
    int c8 = kc * 32 + quad * 8;
    float s8[8] = {0, 0, 0, 0, 0, 0, 0, 0};
#pragma unroll
    for (int sp = 0; sp < KS; ++sp) {
      uint4 v = *(const uint4*)(Opart + (size_t)(sp * NT + arow) * DM + c8);
      unsigned vv[4] = {v.x, v.y, v.z, v.w};
#pragma unroll
      for (int j = 0; j < 4; ++j) {
        s8[2 * j]     += __builtin_bit_cast(float, vv[j] << 16);
        s8[2 * j + 1] += __builtin_bit_cast(float, vv[j] & 0xffff0000u);
      }
    }
    unsigned short af8[8];
#pragma unroll
    for (int j = 0; j < 8; ++j) af8[j] = f2b(s8[j] * inv);
    bf16x8 af = ld_bf8(af8);
#pragma unroll
    for (int nt = 0; nt < 2; ++nt) {
      bf16x8 bf = ld_bf8(Brow + (size_t)nt * 16 * DM + kc * 32);
      acc[nt] = mfma16(af, bf, acc[nt]);
    }
  }
#pragma unroll
  for (int nt = 0; nt < 2; ++nt)
#pragma unroll
    for (int r = 0; r < 4; ++r) {
      int row = m0 + w * 16 + quad * 4 + r;
      int col = cc0 + nt * 16 + ln;
      out[(size_t)row * DM + col] = acc[nt][r] + bo[col];
    }
}

// ---------------- launcher ----------------
extern "C" void kernel_launch(void* const* d_in, const int* in_sizes, int n_in,
                              void* d_out, int out_size, void* d_ws, size_t ws_size,
                              hipStream_t stream) {
  const float* x  = (const float*)d_in[0];
  const float* g  = (const float*)d_in[1];
  const float* Wq = (const float*)d_in[2];
  const float* Wk = (const float*)d_in[3];
  const float* Wv = (const float*)d_in[4];
  const float* Wo = (const float*)d_in[5];
  const float* bo = (const float*)d_in[6];
  float* out = (float*)d_out;

  char* ws = (char*)d_ws;
  const size_t SIG_OFF = 0;
  const size_t WT_OFF  = 16384;
  const size_t QB_OFF  = WT_OFF + (size_t)1280 * DM * 2;            // +0.82 MB
  const size_t KF_OFF  = QB_OFF + (size_t)NH * NT * DHP * 2;        // +4.19 MB
  const size_t VF_OFF  = KF_OFF + (size_t)NH * NT * DHP * 2;        // +4.19 MB
  const size_t OP_OFF  = VF_OFF + (size_t)NH * 48 * NT * 2;         // +3.15 MB
  const size_t LP_OFF  = OP_OFF + (size_t)KS * NT * DM * 2;         // +10.49 MB
  unsigned char* sigb  = (unsigned char*)(ws + SIG_OFF);
  unsigned short* Wt   = (unsigned short*)(ws + WT_OFF);
  unsigned short* Qb   = (unsigned short*)(ws + QB_OFF);
  unsigned short* Kf   = (unsigned short*)(ws + KF_OFF);
  unsigned short* Vf   = (unsigned short*)(ws + VF_OFF);
  unsigned short* Opart= (unsigned short*)(ws + OP_OFF);
  float* Lpart         = (float*)(ws + LP_OFF);

  // K pads (d 40..63) must be zero; Q pads poison (x K-zeros = 0); Vf ot=2
  // ln 8..15 poison feeds only discarded d=40..47 (0xAA bf16 is tiny, no NaN).
  hipMemsetAsync(ws + KF_OFF, 0, (size_t)NH * NT * DHP * 2, stream);

  prep_kernel<<<116, 256, 0, stream>>>(g, Wq, Wk, Wv, Wo, sigb, Wt);
  qkv_gemm<<<dim3(64, 15), 256, 0, stream>>>(x, Wt, Qb, Kf, Vf);
  attn_kernel<<<dim3(32, NH, KS), 256, 0, stream>>>(Qb, Kf, Vf, sigb, Opart, Lpart);
  out_gemm<<<dim3(64, 10), 256, 0, stream>>>(Opart, Lpart, Wt, bo, out);
}